// Round 1
// baseline (204.258 us; speedup 1.0000x reference)
//
#include <hip/hip_runtime.h>

#define NB   16
#define NSQ  1024
#define NSKV 1024
#define ND   256

typedef __bf16    bf16x8 __attribute__((ext_vector_type(8)));
typedef float     f32x4  __attribute__((ext_vector_type(4)));
typedef _Float16  f16x4  __attribute__((ext_vector_type(4)));

#define EST 268   // e-park LDS row stride in f16 elems (536 B): kg groups land on disjoint banks

// ---- merged prep: cvt K->bf16 in MFMA-FRAGMENT ORDER | pack mask bits | zero colsum | zero out0
// Kbf layout: element index i (one bf16x8 = 16 B) =
//   (((b*64 + kvblk)*8 + dc)*64 + kg*16 + m)
// holding K[b][kvblk*16 + m][dc*32 + kg*8 .. +8].  A wave in attn_fused reads
// fragment (c,dc) as kf[(c*8+dc)*64 + lane] -- fully coalesced 1 KB loads, no LDS staging.
// grid = 2048 + 4096 + 64 + 16 = 6224 blocks x 256 thr; branch is block-uniform.
__global__ __launch_bounds__(256) void prep_kernel(
    const float* __restrict__ K, __bf16* __restrict__ Kbf,
    const int* __restrict__ mask, unsigned* __restrict__ mw,
    float* __restrict__ colsum, float* __restrict__ out0)
{
    const int bid = blockIdx.x;
    const int tid = threadIdx.x;
    if (bid < 2048) {
        // K (f32, row-major) -> bf16 fragment-ordered; one bf16x8 per thread.
        const int i    = bid * 256 + tid;
        const int lane = i & 63;
        const int m    = lane & 15;
        const int kg   = lane >> 4;
        const int dc   = (i >> 6) & 7;
        const int kvb  = (i >> 9) & 63;
        const int b    = i >> 15;
        const float* s = K + ((size_t)(b * NSKV + kvb * 16 + m)) * ND + dc * 32 + kg * 8;
        float4 a = *(const float4*)s;
        float4 c = *(const float4*)(s + 4);
        bf16x8 o;
        o[0] = (__bf16)a.x; o[1] = (__bf16)a.y; o[2] = (__bf16)a.z; o[3] = (__bf16)a.w;
        o[4] = (__bf16)c.x; o[5] = (__bf16)c.y; o[6] = (__bf16)c.z; o[7] = (__bf16)c.w;
        ((bf16x8*)Kbf)[i] = o;
    } else if (bid < 2048 + 4096) {
        // mask -> bits: mw[row*64 + h*16 + m], bit c = mask[row][h*256+c*16+m]!=0
        const int row = (bid - 2048) * 4 + (tid >> 6);
        const int l   = tid & 63;
        const int4* mrow = (const int4*)(mask + (size_t)row * NSKV) + l * 4;
        unsigned w = 0;
        #pragma unroll
        for (int v = 0; v < 4; ++v) {
            int4 mv = mrow[v];
            w |= (mv.x != 0 ? 1u : 0u) << (v * 4 + 0);
            w |= (mv.y != 0 ? 1u : 0u) << (v * 4 + 1);
            w |= (mv.z != 0 ? 1u : 0u) << (v * 4 + 2);
            w |= (mv.w != 0 ? 1u : 0u) << (v * 4 + 3);
        }
        const int m    = l & 15;
        const int base = l & 48;
        unsigned out = 0;
        #pragma unroll
        for (int c = 0; c < 16; ++c) {
            unsigned v = (unsigned)__shfl((int)w, base | c);
            out |= ((v >> m) & 1u) << c;
        }
        mw[(size_t)row * 64 + l] = out;
    } else if (bid < 2048 + 4096 + 64) {
        colsum[(bid - 6144) * 256 + tid] = 0.f;
    } else {
        out0[(bid - 6208) * 256 + tid] = 0.f;
    }
}

// ---- main fused kernel ----
// Block = 256 thr (4 waves) = one 16-q-row tile; wave h owns k-quarter
// [h*256,+256).  K arrives PRE-ARRANGED in MFMA fragment order, so the main
// loop is: coalesced global bf16x8 loads (L2-resident) -> MFMA -> exp -> park
// e straight into wave-private LDS.  No ds_write/ds_read staging round-trip,
// no barriers in the main loop.  LDS is only the 16x268-f16 e-transpose
// buffer per wave (~34.5 KB total) => 4 blocks/CU, 16 waves/CU.
__global__ __launch_bounds__(256, 4) void attn_fused(
    const float* __restrict__ Q, const __bf16* __restrict__ Kbf,
    const unsigned* __restrict__ mw, float* __restrict__ out_p,
    float* __restrict__ colsum)
{
    const int b    = blockIdx.x >> 6;
    const int qt   = blockIdx.x & 63;
    const int q0   = qt * 16;
    const int tid  = threadIdx.x;
    const int lane = tid & 63;
    const int h    = tid >> 6;       // wave id = k-quarter
    const int m    = lane & 15;      // MFMA A-row / B-col / C-col
    const int kg   = lane >> 4;      // quad: d-slice for A/B, row-group for C

    __shared__ __attribute__((aligned(16))) _Float16 epark[4][16 * EST]; // 34.3 KB
    __shared__ float Zs[4][16];
    __shared__ float invZs[16];

    _Float16* myE = &epark[h][0];

    // ---- A fragments: the block's 16 Q rows, f32 -> bf16 once ----
    bf16x8 afrag[8];
    {
        const float* qbase = Q + ((size_t)(b * NSQ + q0 + m)) * ND;
        #pragma unroll
        for (int dc = 0; dc < 8; ++dc) {
            const float* p4 = qbase + dc * 32 + kg * 8;
            float4 x = *(const float4*)(p4);
            float4 y = *(const float4*)(p4 + 4);
            bf16x8 a;
            a[0] = (__bf16)x.x; a[1] = (__bf16)x.y; a[2] = (__bf16)x.z; a[3] = (__bf16)x.w;
            a[4] = (__bf16)y.x; a[5] = (__bf16)y.y; a[6] = (__bf16)y.z; a[7] = (__bf16)y.w;
            afrag[dc] = a;
        }
    }

    // ---- mask words: 4 per lane, covers the whole loop ----
    unsigned mword[4];
    #pragma unroll
    for (int i = 0; i < 4; ++i)
        mword[i] = mw[(size_t)(b * NSQ + q0 + kg * 4 + i) * 64 + h * 16 + m];

    // fragment stream base for this wave's kv quarter
    const bf16x8* kf = (const bf16x8*)Kbf + ((size_t)(b * 64 + h * 16) * 8) * 64 + lane;

    float zacc[4] = {0.f, 0.f, 0.f, 0.f};
    bf16x8 fA[8], fB[8];

    #define LDFRAG(g, c) { \
        _Pragma("unroll") \
        for (int dc = 0; dc < 8; ++dc) \
            (g)[dc] = kf[((c) * 8 + dc) * 64]; }

    #define COMPUTE(g, c) { \
        f32x4 acc = {0.f, 0.f, 0.f, 0.f}; \
        _Pragma("unroll") \
        for (int dc = 0; dc < 8; ++dc) \
            acc = __builtin_amdgcn_mfma_f32_16x16x32_bf16(afrag[dc], (g)[dc], acc, 0, 0, 0); \
        _Pragma("unroll") \
        for (int i = 0; i < 4; ++i) { \
            float e = ((mword[i] >> (c)) & 1u) ? __expf(__expf(acc[i]) * 0.0625f) : 0.f; \
            zacc[i] += e; \
            myE[(kg * 4 + i) * EST + (c) * 16 + m] = (_Float16)e; \
        } }

    // prologue: chunk 0 fragments in regs; then prefetch-1-deep double buffer
    LDFRAG(fA, 0);

    #pragma unroll
    for (int cc = 0; cc < 16; cc += 2) {
        LDFRAG(fB, cc + 1);                 // prefetch while computing cc
        COMPUTE(fA, cc);
        if (cc + 2 < 16) LDFRAG(fA, cc + 2);
        COMPUTE(fB, cc + 1);
    }

    // ---- Z: reduce over 16 m-lanes, publish per-wave partials ----
    #pragma unroll
    for (int i = 0; i < 4; ++i) {
        float z = zacc[i];
        z += __shfl_xor(z, 1);
        z += __shfl_xor(z, 2);
        z += __shfl_xor(z, 4);
        z += __shfl_xor(z, 8);
        if (m == 0) Zs[h][kg * 4 + i] = z;
    }
    __syncthreads();
    if (tid < 16)
        invZs[tid] = 1.0f / (Zs[0][tid] + Zs[1][tid] + Zs[2][tid] + Zs[3][tid]);
    __syncthreads();

    // ---- write phase: full 1KB contiguous stores; colsum in-pass ----
    float csum[4] = {0.f, 0.f, 0.f, 0.f};
    float* prow = out_p + (size_t)(b * NSQ + q0) * NSKV + h * 256 + lane * 4;
    #pragma unroll
    for (int s = 0; s < 16; ++s) {
        f16x4 ev = *(const f16x4*)&myE[s * EST + lane * 4];
        const float iz = invZs[s];
        float4 pv;
        pv.x = (float)ev[0] * iz; pv.y = (float)ev[1] * iz;
        pv.z = (float)ev[2] * iz; pv.w = (float)ev[3] * iz;
        *(float4*)(prow + (size_t)s * NSKV) = pv;
        csum[0] += pv.x; csum[1] += pv.y; csum[2] += pv.z; csum[3] += pv.w;
    }
    #pragma unroll
    for (int j = 0; j < 4; ++j)
        atomicAdd(&colsum[b * NSKV + h * 256 + lane * 4 + j], csum[j]);

    #undef LDFRAG
    #undef COMPUTE
}

// out[b,d] = sum_k colsum[b,k] * V[b,k,d]; 1024 blocks, 16 k-rows each.
__global__ __launch_bounds__(256) void attn_out_kernel(
    const float* __restrict__ colsum, const float* __restrict__ V,
    float* __restrict__ out)
{
    const int b  = blockIdx.x >> 6;
    const int ks = (blockIdx.x & 63) << 4;
    const int d  = threadIdx.x;
    float acc = 0.f;
    #pragma unroll
    for (int k = 0; k < 16; ++k) {
        acc += colsum[b * NSKV + ks + k] * V[((size_t)(b * NSKV + ks + k)) * ND + d];
    }
    atomicAdd(&out[b * ND + d], acc);
}

extern "C" void kernel_launch(void* const* d_in, const int* in_sizes, int n_in,
                              void* d_out, int out_size, void* d_ws, size_t ws_size,
                              hipStream_t stream)
{
    (void)in_sizes; (void)n_in; (void)out_size; (void)ws_size;
    const float* Q    = (const float*)d_in[0];
    const float* K    = (const float*)d_in[1];
    const float* V    = (const float*)d_in[2];
    const int*   mask = (const int*)d_in[3];

    float* out0 = (float*)d_out;            // (B, D) = 4096 floats
    float* p    = out0 + NB * ND;           // p_attn (B, SQ, SKV)

    float*    colsum = (float*)d_ws;                               // 64 KB
    __bf16*   Kbf    = (__bf16*)((char*)d_ws + (64 << 10));        // 8.4 MB, fragment-ordered
    unsigned* mwbits = (unsigned*)((char*)d_ws + (64 << 10) + (size_t)NB * NSKV * ND * 2); // 4.2 MB

    prep_kernel<<<6224, 256, 0, stream>>>(K, Kbf, mask, mwbits, colsum, out0);
    attn_fused<<<NB * 64, 256, 0, stream>>>(Q, Kbf, mwbits, p, colsum);
    attn_out_kernel<<<NB * 64, 256, 0, stream>>>(colsum, V, out0);
}

// Round 2
// 202.789 us; speedup vs baseline: 1.0072x; 1.0072x over previous
//
#include <hip/hip_runtime.h>

#define NB   16
#define NSQ  1024
#define NSKV 1024
#define ND   256

typedef __bf16    bf16x8 __attribute__((ext_vector_type(8)));
typedef float     f32x4  __attribute__((ext_vector_type(4)));
typedef _Float16  f16x4  __attribute__((ext_vector_type(4)));

#define EST 268   // e-park LDS row stride in f16 elems (536 B)

// ---- merged prep: cvt K->bf16 in MFMA-FRAGMENT ORDER | pack mask bits | zero colsum | zero out0
// Kbf layout: bf16x8 index i = (((b*64 + kvblk)*8 + dc)*64 + kg*16 + m)
// holding K[b][kvblk*16 + m][dc*32 + kg*8 .. +8].
__global__ __launch_bounds__(256) void prep_kernel(
    const float* __restrict__ K, __bf16* __restrict__ Kbf,
    const int* __restrict__ mask, unsigned* __restrict__ mw,
    float* __restrict__ colsum, float* __restrict__ out0)
{
    const int bid = blockIdx.x;
    const int tid = threadIdx.x;
    if (bid < 2048) {
        const int i    = bid * 256 + tid;
        const int lane = i & 63;
        const int m    = lane & 15;
        const int kg   = lane >> 4;
        const int dc   = (i >> 6) & 7;
        const int kvb  = (i >> 9) & 63;
        const int b    = i >> 15;
        const float* s = K + ((size_t)(b * NSKV + kvb * 16 + m)) * ND + dc * 32 + kg * 8;
        float4 a = *(const float4*)s;
        float4 c = *(const float4*)(s + 4);
        bf16x8 o;
        o[0] = (__bf16)a.x; o[1] = (__bf16)a.y; o[2] = (__bf16)a.z; o[3] = (__bf16)a.w;
        o[4] = (__bf16)c.x; o[5] = (__bf16)c.y; o[6] = (__bf16)c.z; o[7] = (__bf16)c.w;
        ((bf16x8*)Kbf)[i] = o;
    } else if (bid < 2048 + 4096) {
        // mask -> bits: mw[row*64 + h*16 + m], bit c = mask[row][h*256+c*16+m]!=0
        const int row = (bid - 2048) * 4 + (tid >> 6);
        const int l   = tid & 63;
        const int4* mrow = (const int4*)(mask + (size_t)row * NSKV) + l * 4;
        unsigned w = 0;
        #pragma unroll
        for (int v = 0; v < 4; ++v) {
            int4 mv = mrow[v];
            w |= (mv.x != 0 ? 1u : 0u) << (v * 4 + 0);
            w |= (mv.y != 0 ? 1u : 0u) << (v * 4 + 1);
            w |= (mv.z != 0 ? 1u : 0u) << (v * 4 + 2);
            w |= (mv.w != 0 ? 1u : 0u) << (v * 4 + 3);
        }
        const int m    = l & 15;
        const int base = l & 48;
        unsigned out = 0;
        #pragma unroll
        for (int c = 0; c < 16; ++c) {
            unsigned v = (unsigned)__shfl((int)w, base | c);
            out |= ((v >> m) & 1u) << c;
        }
        mw[(size_t)row * 64 + l] = out;
    } else if (bid < 2048 + 4096 + 64) {
        colsum[(bid - 6144) * 256 + tid] = 0.f;
    } else {
        out0[(bid - 6208) * 256 + tid] = 0.f;
    }
}

__device__ __forceinline__ void gload_lds16(const void* g, void* l) {
    __builtin_amdgcn_global_load_lds(
        (const __attribute__((address_space(1))) void*)g,
        (__attribute__((address_space(3))) void*)l, 16, 0, 0);
}

// ---- main fused kernel ----
// grid = 512 blocks x 256 thr (4 waves); block g processes q-tiles g and g+512.
// Wave h owns k-quarter [h*256,+256).  K chunks (8 KB, fragment-ordered) are
// DMA'd global->LDS via global_load_lds (async, counted vmcnt, wave-private,
// NO barriers in the main loop).  Tile t's 16 p-row stores are interleaved
// one-per-chunk into tile t+1's main loop so the 64 MB p write stream overlaps
// the read/MFMA phase instead of bursting at the kernel tail.
// vmcnt(8) is reorder-safe: per iteration exactly {<=1 store, 8 DMA} issue, and
// vmcnt retires strictly in issue order.
__global__ __launch_bounds__(256, 2) void attn_fused(
    const float* __restrict__ Q, const __bf16* __restrict__ Kbf,
    const unsigned* __restrict__ mw, float* __restrict__ out_p,
    float* __restrict__ colsum)
{
    const int tid  = threadIdx.x;
    const int lane = tid & 63;
    const int h    = tid >> 6;       // wave id = k-quarter
    const int m    = lane & 15;      // MFMA A-row / B-col / C-col
    const int kg   = lane >> 4;      // quad: d-slice for A/B, row-group for C

    __shared__ __attribute__((aligned(16))) char kbuf[4][2][8192]; // 64 KB staging
    __shared__ float Zs[4][16];
    __shared__ float invZs[16];

    char* buf0 = &kbuf[h][0][0];
    char* buf1 = &kbuf[h][1][0];
    _Float16* myE = (_Float16*)buf0;  // wave-private 16 KB; reused post-loop (needs 8576 B)

    float4 pregs[16];
    float* prow_prev = nullptr;

    #define WAITVM(N) { asm volatile("s_waitcnt vmcnt(" #N ")" ::: "memory"); \
                        __builtin_amdgcn_sched_barrier(0); }

    #define DMA(bufp, c) { \
        const char* _g = kf0 + (size_t)(c) * 8192; \
        _Pragma("unroll") \
        for (int j = 0; j < 8; ++j) \
            gload_lds16(_g + j * 1024, (bufp) + j * 1024); }

    #define COMPUTE(bufp, c) { \
        f32x4 acc = {0.f, 0.f, 0.f, 0.f}; \
        _Pragma("unroll") \
        for (int j = 0; j < 8; ++j) { \
            bf16x8 bfr = *(const bf16x8*)((bufp) + j * 1024 + lane * 16); \
            acc = __builtin_amdgcn_mfma_f32_16x16x32_bf16(afrag[j], bfr, acc, 0, 0, 0); \
        } \
        _Pragma("unroll") \
        for (int i = 0; i < 4; ++i) { \
            float e = ((mword[i] >> (c)) & 1u) ? __expf(__expf(acc[i]) * 0.0625f) : 0.f; \
            zacc[i] += e; \
            ebuf[c][i] = (_Float16)e; \
        } }

    for (int t = 0; t < 2; ++t) {
        const int tile = (int)blockIdx.x + t * 512;
        const int b    = tile >> 6;
        const int q0   = (tile & 63) * 16;
        const bool prev = (t != 0);

        // ---- A fragments: 16 Q rows, f32 -> bf16 ----
        bf16x8 afrag[8];
        {
            const float* qbase = Q + ((size_t)(b * NSQ + q0 + m)) * ND;
            #pragma unroll
            for (int dc = 0; dc < 8; ++dc) {
                const float* p4 = qbase + dc * 32 + kg * 8;
                float4 x = *(const float4*)(p4);
                float4 y = *(const float4*)(p4 + 4);
                bf16x8 a;
                a[0] = (__bf16)x.x; a[1] = (__bf16)x.y; a[2] = (__bf16)x.z; a[3] = (__bf16)x.w;
                a[4] = (__bf16)y.x; a[5] = (__bf16)y.y; a[6] = (__bf16)y.z; a[7] = (__bf16)y.w;
                afrag[dc] = a;
            }
        }

        unsigned mword[4];
        #pragma unroll
        for (int i = 0; i < 4; ++i)
            mword[i] = mw[(size_t)(b * NSQ + q0 + kg * 4 + i) * 64 + h * 16 + m];

        // per-lane global src base for this wave's kv-quarter fragment stream
        const char* kf0 = (const char*)Kbf
                        + ((size_t)(b * 64 + h * 16) * 8 * 64) * 16 + lane * 16;

        float zacc[4] = {0.f, 0.f, 0.f, 0.f};
        f16x4 ebuf[16];

        // prologue: chunks 0,1 in flight; first two prev-tile stores issued
        if (prev) *(float4*)(prow_prev + (size_t)0 * NSKV) = pregs[0];
        DMA(buf0, 0);
        if (prev) *(float4*)(prow_prev + (size_t)1 * NSKV) = pregs[1];
        DMA(buf1, 1);

        #pragma unroll
        for (int cc = 0; cc < 16; ++cc) {
            if (cc < 15) { WAITVM(8); } else { WAITVM(0); }
            char* cbuf = (cc & 1) ? buf1 : buf0;
            COMPUTE(cbuf, cc);
            if (cc < 14) {
                if (prev) *(float4*)(prow_prev + (size_t)(cc + 2) * NSKV) = pregs[cc + 2];
                DMA(cbuf, cc + 2);
            }
        }

        // ---- park e into own-wave staging LDS (now free) for transposed reads ----
        #pragma unroll
        for (int c = 0; c < 16; ++c)
            #pragma unroll
            for (int i = 0; i < 4; ++i)
                myE[(kg * 4 + i) * EST + c * 16 + m] = ebuf[c][i];

        // ---- Z: reduce over 16 m-lanes, publish per-wave partials ----
        #pragma unroll
        for (int i = 0; i < 4; ++i) {
            float z = zacc[i];
            z += __shfl_xor(z, 1);
            z += __shfl_xor(z, 2);
            z += __shfl_xor(z, 4);
            z += __shfl_xor(z, 8);
            if (m == 0) Zs[h][kg * 4 + i] = z;
        }
        __syncthreads();
        if (tid < 16)
            invZs[tid] = 1.0f / (Zs[0][tid] + Zs[1][tid] + Zs[2][tid] + Zs[3][tid]);
        __syncthreads();

        // ---- normalized p rows -> registers; colsum in-pass ----
        float csum[4] = {0.f, 0.f, 0.f, 0.f};
        #pragma unroll
        for (int s = 0; s < 16; ++s) {
            f16x4 ev = *(const f16x4*)&myE[s * EST + lane * 4];
            const float iz = invZs[s];
            float4 pv;
            pv.x = (float)ev[0] * iz; pv.y = (float)ev[1] * iz;
            pv.z = (float)ev[2] * iz; pv.w = (float)ev[3] * iz;
            pregs[s] = pv;
            csum[0] += pv.x; csum[1] += pv.y; csum[2] += pv.z; csum[3] += pv.w;
        }
        #pragma unroll
        for (int j = 0; j < 4; ++j)
            atomicAdd(&colsum[b * NSKV + h * 256 + lane * 4 + j], csum[j]);

        prow_prev = out_p + (size_t)(b * NSQ + q0) * NSKV + h * 256 + lane * 4;
    }

    // epilogue: last tile's stores (unoverlapped tail)
    #pragma unroll
    for (int s = 0; s < 16; ++s)
        *(float4*)(prow_prev + (size_t)s * NSKV) = pregs[s];

    #undef WAITVM
    #undef DMA
    #undef COMPUTE
}

// out[b,d] = sum_k colsum[b,k] * V[b,k,d]; 1024 blocks, 16 k-rows each.
__global__ __launch_bounds__(256) void attn_out_kernel(
    const float* __restrict__ colsum, const float* __restrict__ V,
    float* __restrict__ out)
{
    const int b  = blockIdx.x >> 6;
    const int ks = (blockIdx.x & 63) << 4;
    const int d  = threadIdx.x;
    float acc = 0.f;
    #pragma unroll
    for (int k = 0; k < 16; ++k) {
        acc += colsum[b * NSKV + ks + k] * V[((size_t)(b * NSKV + ks + k)) * ND + d];
    }
    atomicAdd(&out[b * ND + d], acc);
}

extern "C" void kernel_launch(void* const* d_in, const int* in_sizes, int n_in,
                              void* d_out, int out_size, void* d_ws, size_t ws_size,
                              hipStream_t stream)
{
    (void)in_sizes; (void)n_in; (void)out_size; (void)ws_size;
    const float* Q    = (const float*)d_in[0];
    const float* K    = (const float*)d_in[1];
    const float* V    = (const float*)d_in[2];
    const int*   mask = (const int*)d_in[3];

    float* out0 = (float*)d_out;            // (B, D) = 4096 floats
    float* p    = out0 + NB * ND;           // p_attn (B, SQ, SKV)

    float*    colsum = (float*)d_ws;                               // 64 KB
    __bf16*   Kbf    = (__bf16*)((char*)d_ws + (64 << 10));        // 8.4 MB, fragment-ordered
    unsigned* mwbits = (unsigned*)((char*)d_ws + (64 << 10) + (size_t)NB * NSKV * ND * 2); // 4.2 MB

    prep_kernel<<<6224, 256, 0, stream>>>(K, Kbf, mask, mwbits, colsum, out0);
    attn_fused<<<512, 256, 0, stream>>>(Q, Kbf, mwbits, p, colsum);
    attn_out_kernel<<<NB * 64, 256, 0, stream>>>(colsum, V, out0);
}